// Round 8
// baseline (1819.653 us; speedup 1.0000x reference)
//
#include <hip/hip_runtime.h>

#define N_NODES 8192
#define N_EDGES 131072
#define E_DIM 256
#define NE_HALF 4096
#define LOSS_OFF 8388608
#define IDX_OFF 8388611
#define KC_PANEL 384   // OpenBLAS SGEMM_DEFAULT_Q (Zen/Haswell)

// workspace layout (float element offsets)
#define WS_DINV 0
#define WS_EN2 8192
#define WS_LOSS 16384
#define WS_CNT 17408
#define WS_ROWSTART 25600
#define WS_FILL 34816
#define WS_COL 43008
#define WS_XW 174080      // reused as top-k u64 region after agg2
#define WS_H  2271232
#define WS_TEW 4368384
#define WS_QN2 6465536

__global__ void count_kernel(const int* __restrict__ dst, int* __restrict__ cnt) {
    int e = blockIdx.x * blockDim.x + threadIdx.x;
    if (e < N_EDGES) atomicAdd(&cnt[dst[e]], 1);
}

__global__ __launch_bounds__(1024) void scan_kernel(const int* __restrict__ cnt,
                                                    int* __restrict__ rowstart,
                                                    float* __restrict__ dinv) {
    __shared__ int part[1024];
    int t = threadIdx.x;
    int c[8], pre[8];
    int run = 0;
#pragma unroll
    for (int i = 0; i < 8; ++i) {
        c[i] = cnt[t * 8 + i];
        pre[i] = run;
        run += c[i];
    }
    part[t] = run;
    __syncthreads();
    for (int d = 1; d < 1024; d <<= 1) {
        int add = (t >= d) ? part[t - d] : 0;
        __syncthreads();
        part[t] += add;
        __syncthreads();
    }
    int off = (t == 0) ? 0 : part[t - 1];
#pragma unroll
    for (int i = 0; i < 8; ++i) {
        rowstart[t * 8 + i] = off + pre[i];
        dinv[t * 8 + i] = 1.0f / sqrtf((float)(c[i] + 1));
    }
    if (t == 1023) rowstart[8192] = part[1023];
}

__global__ void scatter_kernel(const int* __restrict__ dst,
                               const int* __restrict__ rowstart, int* __restrict__ fill,
                               int* __restrict__ col) {
    int e = blockIdx.x * blockDim.x + threadIdx.x;
    if (e < N_EDGES) {
        int d = dst[e];
        int pos = atomicAdd(&fill[d], 1);
        col[rowstart[d] + pos] = e;
    }
}

__global__ __launch_bounds__(256) void sort_kernel(const int* __restrict__ src,
                                                   const int* __restrict__ rowstart,
                                                   int* __restrict__ col) {
    int i = blockIdx.x * blockDim.x + threadIdx.x;
    if (i >= N_NODES) return;
    int s0 = rowstart[i], s1 = rowstart[i + 1];
    for (int a = s0 + 1; a < s1; ++a) {
        int v = col[a];
        int b = a - 1;
        while (b >= s0 && col[b] > v) { col[b + 1] = col[b]; --b; }
        col[b + 1] = v;
    }
    for (int a = s0; a < s1; ++a) col[a] = src[col[a]];
}

// OpenBLAS-style K blocking with balanced tail; panels joined by plain adds.
__global__ __launch_bounds__(256) void gemm_kernel(const float* __restrict__ X,
                                                   const float* __restrict__ W,
                                                   float* __restrict__ Y, int K) {
    __shared__ float aT[16][68];
    __shared__ float bT[16][68];
    const int t = threadIdx.x;
    const int bm = blockIdx.x * 64;
    const int bn = blockIdx.y * 64;
    float cacc[4][4] = {};
    const int tm = t >> 4, tn = t & 15;
    const int lm = t >> 2, lk = (t & 3) * 4;
    const int bk = t >> 4, bn4 = (t & 15) * 4;
    int kp = 0;
    bool first = true;
    while (kp < K) {
        int rem = K - kp;
        int pl;
        if (rem >= 2 * KC_PANEL) pl = KC_PANEL;
        else if (rem > KC_PANEL) pl = (rem / 2 + 15) & ~15;
        else pl = rem;
        const int kend = kp + pl;
        float pacc[4][4] = {};
        for (int k0 = kp; k0 < kend; k0 += 16) {
            __syncthreads();
            float4 av = *(const float4*)&X[(size_t)(bm + lm) * K + k0 + lk];
            aT[lk + 0][lm] = av.x; aT[lk + 1][lm] = av.y;
            aT[lk + 2][lm] = av.z; aT[lk + 3][lm] = av.w;
            *(float4*)&bT[bk][bn4] = *(const float4*)&W[(size_t)(k0 + bk) * E_DIM + bn + bn4];
            __syncthreads();
#pragma unroll
            for (int k = 0; k < 16; ++k) {
                float4 a = *(const float4*)&aT[k][tm * 4];
                float4 b = *(const float4*)&bT[k][tn * 4];
                float qa[4] = {a.x, a.y, a.z, a.w};
                float ea[4] = {b.x, b.y, b.z, b.w};
#pragma unroll
                for (int i = 0; i < 4; ++i)
#pragma unroll
                    for (int j = 0; j < 4; ++j) pacc[i][j] = fmaf(qa[i], ea[j], pacc[i][j]);
            }
        }
        if (first) {
#pragma unroll
            for (int i = 0; i < 4; ++i)
#pragma unroll
                for (int j = 0; j < 4; ++j) cacc[i][j] = pacc[i][j];
        } else {
#pragma unroll
            for (int i = 0; i < 4; ++i)
#pragma unroll
                for (int j = 0; j < 4; ++j) cacc[i][j] = __fadd_rn(cacc[i][j], pacc[i][j]);
        }
        first = false;
        kp = kend;
    }
#pragma unroll
    for (int i = 0; i < 4; ++i) {
        float4 v = make_float4(cacc[i][0], cacc[i][1], cacc[i][2], cacc[i][3]);
        *(float4*)&Y[(size_t)(bm + tm * 4 + i) * E_DIM + bn + tn * 4] = v;
    }
}

__global__ __launch_bounds__(256) void agg_kernel(const float* __restrict__ xw,
                                                  const int* __restrict__ rowstart,
                                                  const int* __restrict__ col,
                                                  const float* __restrict__ dinv,
                                                  const float* __restrict__ bias,
                                                  float* __restrict__ out, int do_relu) {
    int i = blockIdx.x;
    int c = threadIdx.x;
    float di = dinv[i];
    float acc = 0.0f;
    int s0 = rowstart[i], s1 = rowstart[i + 1];
    for (int j = s0; j < s1; ++j) {
        int s = col[j];
        float nrm = __fmul_rn(dinv[s], di);
        acc = __fadd_rn(acc, __fmul_rn(nrm, xw[(size_t)s * E_DIM + c]));
    }
    acc = __fadd_rn(acc, __fmul_rn(__fmul_rn(di, di), xw[(size_t)i * E_DIM + c]));
    acc = __fadd_rn(acc, bias[c]);
    if (do_relu) acc = fmaxf(acc, 0.0f);
    out[(size_t)i * E_DIM + c] = acc;
}

// numpy-pairwise bitexact squared row norms
__global__ __launch_bounds__(256) void enorm_kernel(const float* __restrict__ e,
                                                    float* __restrict__ out) {
    int t = threadIdx.x;
    int row = blockIdx.x * 16 + (t >> 4);
    int l = t & 15;
    int blk = l >> 3, j = l & 7;
    const float* p = e + (size_t)row * 256 + blk * 128 + j;
    float v = p[0];
    float acc = __fmul_rn(v, v);
#pragma unroll
    for (int i = 1; i < 16; ++i) {
        float w = p[i * 8];
        acc = __fadd_rn(acc, __fmul_rn(w, w));
    }
    acc = __fadd_rn(acc, __shfl_xor(acc, 1, 64));
    acc = __fadd_rn(acc, __shfl_xor(acc, 2, 64));
    acc = __fadd_rn(acc, __shfl_xor(acc, 4, 64));
    acc = __fadd_rn(acc, __shfl_xor(acc, 8, 64));
    if (l == 0) out[row] = acc;
}

__global__ __launch_bounds__(256) void qnorm_kernel(const float* __restrict__ z,
                                                    float* __restrict__ out) {
    int t = threadIdx.x;
    int row = blockIdx.x * 16 + (t >> 4);
    int half = row >> 14, r = row & 16383;
    int b = r >> 8, pp = r & 255;
    int l = t & 15;
    int blk = l >> 3, j = l & 7;
    const float* p = z + (size_t)b * 131072 + (size_t)half * 65536 + pp +
                     (size_t)(blk * 128 + j) * 256;
    float v = p[0];
    float acc = __fmul_rn(v, v);
#pragma unroll
    for (int i = 1; i < 16; ++i) {
        float w = p[(size_t)i * 8 * 256];
        acc = __fadd_rn(acc, __fmul_rn(w, w));
    }
    acc = __fadd_rn(acc, __shfl_xor(acc, 1, 64));
    acc = __fadd_rn(acc, __shfl_xor(acc, 2, 64));
    acc = __fadd_rn(acc, __shfl_xor(acc, 4, 64));
    acc = __fadd_rn(acc, __shfl_xor(acc, 8, 64));
    if (l == 0) out[row] = acc;
}

__device__ __forceinline__ unsigned long long shfl_xor_u64(unsigned long long v, int m) {
    unsigned int lo = (unsigned int)v, hi = (unsigned int)(v >> 32);
    lo = __shfl_xor(lo, m, 64);
    hi = __shfl_xor(hi, m, 64);
    return ((unsigned long long)hi << 32) | lo;
}

// Fused distance + per-part top-k. Scores bit-identical to reference:
// dot = sequential k-ascending fp32 FMA chain; s = fl(fl(|z|^2+|e|^2) - fl(2*dot)).
// Key = (bits(s)<<32)|idx (s>0 always) -> unsigned compare == (s, idx) lexicographic,
// ties to LOWER index. QM = queries per thread; block = 8*QM queries x 4096*2/QM codes.
template <int TK, int QM>
__device__ __forceinline__ void quant_body(const float* __restrict__ z,
                                           const float* __restrict__ emb,
                                           const float* __restrict__ en2,
                                           const float* __restrict__ qn2,
                                           unsigned long long* __restrict__ topWs,
                                           int coff) {
    constexpr int EP = QM / 2;            // code splits
    constexpr int QB = 8 * QM;            // queries per block
    constexpr int EPB = NE_HALF / EP;     // codes per block
    constexpr int NET = EPB / 256;        // 256-code tiles
    constexpr int QPAD = QB + 8;

    __shared__ float eT[32][264];         // [k][e^f(k)], f(k)=k&24
    __shared__ float qS[32][QPAD];        // [k][q]
    __shared__ float sEn2[256];

    const int t = threadIdx.x;
    const int qt = blockIdx.x / EP;
    const int ep = blockIdx.x % EP;
    const int r0 = qt * QB;
    const int b = r0 >> 8;
    const int p0 = r0 & 255;
    const int e00 = ep * EPB;

    const int tq = t >> 5, te = t & 31;
    const int q0 = tq * QM;
    const int e0 = te * 4;                // thread covers e0..e0+3 and 128+e0..+3

    const int sk = (t & 7) * 4;           // eT staging rows sk..sk+3
    const int se = t >> 3;                // eT staging logical e base
    const int cb = se ^ (sk & 24);        // swizzled column base
    const int kq = t >> 3, jq = (t & 7) * 4;  // qS staging

    const float* zb = z + (size_t)b * 131072 + (size_t)coff * 256 + p0;

    float aq[QM];
#pragma unroll
    for (int i = 0; i < QM; ++i) aq[i] = qn2[r0 + q0 + i];

    unsigned long long bk[QM][TK];
#pragma unroll
    for (int i = 0; i < QM; ++i)
#pragma unroll
        for (int j = 0; j < TK; ++j) bk[i][j] = 0xFFFFFFFFFFFFFFFFull;

    for (int et = 0; et < NET; ++et) {
        const int ebase = e00 + et * 256;
        float acc[QM][8] = {};
        for (int kc = 0; kc < 8; ++kc) {
            __syncthreads();
            // stage eT: 256e x 32k, transposed, XOR-swizzled (write-conflict-free)
#pragma unroll
            for (int i = 0; i < 8; ++i) {
                float4 v = *(const float4*)&emb[(size_t)(ebase + se + 32 * i) * 256 + kc * 32 + sk];
                eT[sk + 0][cb + 32 * i] = v.x;
                eT[sk + 1][cb + 32 * i] = v.y;
                eT[sk + 2][cb + 32 * i] = v.z;
                eT[sk + 3][cb + 32 * i] = v.w;
            }
            // stage qS: QBq x 32k from z (coalesced float4 over p)
            {
                float4 v = *(const float4*)&zb[(size_t)(kc * 32 + kq) * 256 + jq];
                *(float4*)&qS[kq][jq] = v;
                if (QM == 8) {
                    float4 w = *(const float4*)&zb[(size_t)(kc * 32 + kq) * 256 + jq + 32];
                    *(float4*)&qS[kq][jq + 32] = w;
                }
            }
            if (kc == 0) sEn2[t] = en2[ebase + t];
            __syncthreads();
#pragma unroll
            for (int k = 0; k < 32; ++k) {
                const int f = k & 24;
                const int c1 = e0 ^ f;
                float4 ea = *(const float4*)&eT[k][c1];
                float4 eb = *(const float4*)&eT[k][128 + c1];
                float ev[8] = {ea.x, ea.y, ea.z, ea.w, eb.x, eb.y, eb.z, eb.w};
                float qv[QM];
                {
                    float4 qa = *(const float4*)&qS[k][q0];
                    qv[0] = qa.x; qv[1] = qa.y; qv[2] = qa.z; qv[3] = qa.w;
                    if (QM == 8) {
                        float4 qb2 = *(const float4*)&qS[k][q0 + 4];
                        qv[4] = qb2.x; qv[5] = qb2.y; qv[6] = qb2.z; qv[7] = qb2.w;
                    }
                }
#pragma unroll
                for (int i = 0; i < QM; ++i)
#pragma unroll
                    for (int j = 0; j < 8; ++j)
                        acc[i][j] = fmaf(qv[i], ev[j], acc[i][j]);
            }
        }
        // score + insert (gi ascending within thread)
#pragma unroll
        for (int j = 0; j < 8; ++j) {
            const int le = (j < 4) ? (e0 + j) : (128 + e0 + j - 4);
            float e2 = sEn2[le];
            unsigned int gi = (unsigned int)(ebase + le);
#pragma unroll
            for (int i = 0; i < QM; ++i) {
                float t1 = __fadd_rn(aq[i], e2);
                float s = __fsub_rn(t1, __fmul_rn(2.0f, acc[i][j]));
                unsigned long long key =
                    ((unsigned long long)__float_as_uint(s) << 32) | gi;
                if (key < bk[i][TK - 1]) {
                    bk[i][TK - 1] = key;
#pragma unroll
                    for (int mm = TK - 1; mm > 0; --mm)
                        if (bk[i][mm] < bk[i][mm - 1]) {
                            unsigned long long tmp = bk[i][mm];
                            bk[i][mm] = bk[i][mm - 1];
                            bk[i][mm - 1] = tmp;
                        }
                }
            }
        }
    }

    // butterfly merge across the 32 lanes sharing each q-group
#pragma unroll
    for (int mw = 1; mw < 32; mw <<= 1) {
#pragma unroll
        for (int i = 0; i < QM; ++i) {
            unsigned long long ms[TK], os[TK], ns[TK];
#pragma unroll
            for (int j = 0; j < TK; ++j) {
                ms[j] = bk[i][j];
                os[j] = shfl_xor_u64(bk[i][j], mw);
            }
#pragma unroll
            for (int x = 0; x < TK; ++x) {
                bool ta = ms[0] < os[0];
                ns[x] = ta ? ms[0] : os[0];
#pragma unroll
                for (int y = 0; y < TK - 1; ++y) {
                    ms[y] = ta ? ms[y + 1] : ms[y];
                    os[y] = ta ? os[y] : os[y + 1];
                }
            }
#pragma unroll
            for (int j = 0; j < TK; ++j) bk[i][j] = ns[j];
        }
    }

    if (te == 0) {
#pragma unroll
        for (int i = 0; i < QM; ++i) {
            unsigned long long* dst = topWs + ((size_t)(r0 + q0 + i) * EP + ep) * TK;
#pragma unroll
            for (int j = 0; j < TK; ++j) dst[j] = bk[i][j];
        }
    }
}

__global__ __launch_bounds__(256, 4) void quantA_kernel(const float* __restrict__ z,
                                                        const float* __restrict__ emb,
                                                        const float* __restrict__ en2,
                                                        const float* __restrict__ qn2,
                                                        unsigned long long* __restrict__ topWs) {
    quant_body<4, 4>(z, emb, en2, qn2, topWs, 0);
}

__global__ __launch_bounds__(256, 3) void quantN_kernel(const float* __restrict__ z,
                                                        const float* __restrict__ emb,
                                                        const float* __restrict__ en2,
                                                        const float* __restrict__ qn2,
                                                        unsigned long long* __restrict__ topWs) {
    quant_body<1, 8>(z, emb, en2, qn2, topWs, 256);
}

// merge 2 sorted-4 lists -> top4; straight-through output + loss (adjective half)
__global__ __launch_bounds__(256) void mergeA_kernel(const unsigned long long* __restrict__ topWs,
                                                     const float* __restrict__ z,
                                                     const float* __restrict__ emb,
                                                     float* __restrict__ out,
                                                     float* __restrict__ lossAcc) {
    __shared__ int sIdx[32][4];
    __shared__ float red[256];
    const int t = threadIdx.x;
    const int r0 = blockIdx.x * 32;
    const int b = r0 >> 8, p0 = r0 & 255;
    if (t < 32) {
        const unsigned long long* src = topWs + (size_t)(r0 + t) * 8;
        unsigned long long ms[4], os[4], ns[4];
#pragma unroll
        for (int j = 0; j < 4; ++j) { ms[j] = src[j]; os[j] = src[4 + j]; }
#pragma unroll
        for (int x = 0; x < 4; ++x) {
            bool ta = ms[0] < os[0];
            ns[x] = ta ? ms[0] : os[0];
#pragma unroll
            for (int y = 0; y < 3; ++y) {
                ms[y] = ta ? ms[y + 1] : ms[y];
                os[y] = ta ? os[y] : os[y + 1];
            }
        }
        int pp = p0 + t;
#pragma unroll
        for (int j = 0; j < 4; ++j) {
            int idx = (int)(unsigned int)(ns[j] & 0xffffffffull);
            sIdx[t][j] = idx;
            out[IDX_OFF + (size_t)b * 1280 + pp * 4 + j] = (float)idx;
        }
    }
    __syncthreads();
    float lsum = 0.0f;
    {
        const int q = t & 31;
        const int pp = p0 + q;
        float* ob = out + (size_t)b * 131072 + pp;
        const float* zb = z + (size_t)b * 131072 + pp;
        int id[4];
#pragma unroll
        for (int j = 0; j < 4; ++j) id[j] = sIdx[q][j];
        for (int i = 0; i < 32; ++i) {
            int c = (t >> 5) + 8 * i;
            float v = 0.0f;
#pragma unroll
            for (int j = 0; j < 4; ++j) v = __fadd_rn(v, emb[(size_t)id[j] * 256 + c]);
            v *= 0.25f;
            float dd = v - zb[(size_t)c * 256];
            lsum += dd * dd;
            ob[(size_t)c * 256] = v;
        }
    }
    red[t] = lsum;
    __syncthreads();
    for (int s2 = 128; s2 > 0; s2 >>= 1) {
        if (t < s2) red[t] += red[t + s2];
        __syncthreads();
    }
    if (t == 0) atomicAdd(lossAcc, red[0]);
}

// min of 4 parts; straight-through output + loss (noun half)
__global__ __launch_bounds__(256) void mergeN_kernel(const unsigned long long* __restrict__ topWs,
                                                     const float* __restrict__ z,
                                                     const float* __restrict__ emb,
                                                     float* __restrict__ out,
                                                     float* __restrict__ lossAcc) {
    __shared__ int sIdx[32];
    __shared__ float red[256];
    const int t = threadIdx.x;
    const int r0 = blockIdx.x * 32;
    const int b = r0 >> 8, p0 = r0 & 255;
    if (t < 32) {
        const unsigned long long* src = topWs + (size_t)(r0 + t) * 4;
        unsigned long long k0 = src[0], k1 = src[1], k2 = src[2], k3 = src[3];
        unsigned long long m0 = (k0 < k1) ? k0 : k1;
        unsigned long long m1 = (k2 < k3) ? k2 : k3;
        unsigned long long mm = (m0 < m1) ? m0 : m1;
        int idx = (int)(unsigned int)(mm & 0xffffffffull);
        sIdx[t] = idx;
        out[IDX_OFF + (size_t)b * 1280 + 1024 + p0 + t] = (float)idx;
    }
    __syncthreads();
    float lsum = 0.0f;
    {
        const int q = t & 31;
        const int pp = p0 + q;
        float* ob = out + (size_t)b * 131072 + 65536 + pp;
        const float* zb = z + (size_t)b * 131072 + 65536 + pp;
        int id = sIdx[q];
        for (int i = 0; i < 32; ++i) {
            int c = (t >> 5) + 8 * i;
            float v = emb[(size_t)id * 256 + c];
            float dd = v - zb[(size_t)c * 256];
            lsum += dd * dd;
            ob[(size_t)c * 256] = v;
        }
    }
    red[t] = lsum;
    __syncthreads();
    for (int s2 = 128; s2 > 0; s2 >>= 1) {
        if (t < s2) red[t] += red[t + s2];
        __syncthreads();
    }
    if (t == 0) atomicAdd(lossAcc, red[0]);
}

__global__ void final_kernel(const float* __restrict__ lossAcc, float* __restrict__ out) {
    if (threadIdx.x == 0 && blockIdx.x == 0) {
        const float inv = 1.0f / 4194304.0f;
        float mseA = lossAcc[0] * inv;
        float mseN = lossAcc[1] * inv;
        float quan = mseA + mseN;
        float commit = 0.25f * mseA + 0.25f * mseN;
        out[LOSS_OFF + 0] = quan + commit;
        out[LOSS_OFF + 1] = commit;
        out[LOSS_OFF + 2] = quan;
    }
}

extern "C" void kernel_launch(void* const* d_in, const int* in_sizes, int n_in,
                              void* d_out, int out_size, void* d_ws, size_t ws_size,
                              hipStream_t stream) {
    const float* z = (const float*)d_in[0];
    const float* node_x = (const float*)d_in[1];
    const int* ei = (const int*)d_in[2];
    const float* W1 = (const float*)d_in[3];
    const float* b1 = (const float*)d_in[4];
    const float* W2 = (const float*)d_in[5];
    const float* b2 = (const float*)d_in[6];
    float* out = (float*)d_out;
    float* ws = (float*)d_ws;

    float* dinv = ws + WS_DINV;
    float* en2 = ws + WS_EN2;
    float* lossAcc = ws + WS_LOSS;
    int* cnt = (int*)(ws + WS_CNT);
    int* rowstart = (int*)(ws + WS_ROWSTART);
    int* fill = (int*)(ws + WS_FILL);
    int* col = (int*)(ws + WS_COL);
    float* xw = ws + WS_XW;
    float* h = ws + WS_H;
    float* tew = ws + WS_TEW;
    float* qn2 = ws + WS_QN2;
    unsigned long long* topA = (unsigned long long*)(ws + WS_XW);  // reuse xw after agg2
    unsigned long long* topN = topA + 131072;

    const int* srcp = ei;
    const int* dstp = ei + N_EDGES;

    hipMemsetAsync(cnt, 0, N_NODES * sizeof(int), stream);
    hipMemsetAsync(fill, 0, N_NODES * sizeof(int), stream);
    hipMemsetAsync(lossAcc, 0, 2 * sizeof(float), stream);

    count_kernel<<<N_EDGES / 256, 256, 0, stream>>>(dstp, cnt);
    scan_kernel<<<1, 1024, 0, stream>>>(cnt, rowstart, dinv);
    scatter_kernel<<<N_EDGES / 256, 256, 0, stream>>>(dstp, rowstart, fill, col);
    sort_kernel<<<N_NODES / 256, 256, 0, stream>>>(srcp, rowstart, col);

    qnorm_kernel<<<2048, 256, 0, stream>>>(z, qn2);

    gemm_kernel<<<dim3(128, 4), 256, 0, stream>>>(node_x, W1, xw, 1024);
    agg_kernel<<<N_NODES, 256, 0, stream>>>(xw, rowstart, col, dinv, b1, h, 1);
    gemm_kernel<<<dim3(128, 4), 256, 0, stream>>>(h, W2, xw, 256);
    agg_kernel<<<N_NODES, 256, 0, stream>>>(xw, rowstart, col, dinv, b2, tew, 0);

    enorm_kernel<<<512, 256, 0, stream>>>(tew, en2);

    quantA_kernel<<<1024, 256, 0, stream>>>(z, tew, en2, qn2, topA);
    quantN_kernel<<<1024, 256, 0, stream>>>(z, tew + (size_t)NE_HALF * E_DIM,
                                            en2 + NE_HALF, qn2 + 16384, topN);
    mergeA_kernel<<<512, 256, 0, stream>>>(topA, z, tew, out, lossAcc + 0);
    mergeN_kernel<<<512, 256, 0, stream>>>(topN, z, tew + (size_t)NE_HALF * E_DIM,
                                           out, lossAcc + 1);
    final_kernel<<<1, 64, 0, stream>>>(lossAcc, out);
}

// Round 9
// 1518.927 us; speedup vs baseline: 1.1980x; 1.1980x over previous
//
#include <hip/hip_runtime.h>

#define N_NODES 8192
#define N_EDGES 131072
#define E_DIM 256
#define NE_HALF 4096
#define LOSS_OFF 8388608
#define IDX_OFF 8388611
#define KC_PANEL 384   // OpenBLAS SGEMM_DEFAULT_Q (Zen/Haswell)

// workspace layout (float element offsets)
#define WS_DINV 0
#define WS_EN2 8192
#define WS_LOSS 16384
#define WS_CNT 17408
#define WS_ROWSTART 25600
#define WS_FILL 34816
#define WS_COL 43008
#define WS_XW 174080      // reused as top-k u64 region after agg2
#define WS_H  2271232
#define WS_TEW 4368384
#define WS_QN2 6465536

__global__ void count_kernel(const int* __restrict__ dst, int* __restrict__ cnt) {
    int e = blockIdx.x * blockDim.x + threadIdx.x;
    if (e < N_EDGES) atomicAdd(&cnt[dst[e]], 1);
}

__global__ __launch_bounds__(1024) void scan_kernel(const int* __restrict__ cnt,
                                                    int* __restrict__ rowstart,
                                                    float* __restrict__ dinv) {
    __shared__ int part[1024];
    int t = threadIdx.x;
    int c[8], pre[8];
    int run = 0;
#pragma unroll
    for (int i = 0; i < 8; ++i) {
        c[i] = cnt[t * 8 + i];
        pre[i] = run;
        run += c[i];
    }
    part[t] = run;
    __syncthreads();
    for (int d = 1; d < 1024; d <<= 1) {
        int add = (t >= d) ? part[t - d] : 0;
        __syncthreads();
        part[t] += add;
        __syncthreads();
    }
    int off = (t == 0) ? 0 : part[t - 1];
#pragma unroll
    for (int i = 0; i < 8; ++i) {
        rowstart[t * 8 + i] = off + pre[i];
        dinv[t * 8 + i] = 1.0f / sqrtf((float)(c[i] + 1));
    }
    if (t == 1023) rowstart[8192] = part[1023];
}

__global__ void scatter_kernel(const int* __restrict__ dst,
                               const int* __restrict__ rowstart, int* __restrict__ fill,
                               int* __restrict__ col) {
    int e = blockIdx.x * blockDim.x + threadIdx.x;
    if (e < N_EDGES) {
        int d = dst[e];
        int pos = atomicAdd(&fill[d], 1);
        col[rowstart[d] + pos] = e;
    }
}

__global__ __launch_bounds__(256) void sort_kernel(const int* __restrict__ src,
                                                   const int* __restrict__ rowstart,
                                                   int* __restrict__ col) {
    int i = blockIdx.x * blockDim.x + threadIdx.x;
    if (i >= N_NODES) return;
    int s0 = rowstart[i], s1 = rowstart[i + 1];
    for (int a = s0 + 1; a < s1; ++a) {
        int v = col[a];
        int b = a - 1;
        while (b >= s0 && col[b] > v) { col[b + 1] = col[b]; --b; }
        col[b + 1] = v;
    }
    for (int a = s0; a < s1; ++a) col[a] = src[col[a]];
}

// OpenBLAS-style K blocking with balanced tail; panels joined by plain adds.
__global__ __launch_bounds__(256) void gemm_kernel(const float* __restrict__ X,
                                                   const float* __restrict__ W,
                                                   float* __restrict__ Y, int K) {
    __shared__ float aT[16][68];
    __shared__ float bT[16][68];
    const int t = threadIdx.x;
    const int bm = blockIdx.x * 64;
    const int bn = blockIdx.y * 64;
    float cacc[4][4] = {};
    const int tm = t >> 4, tn = t & 15;
    const int lm = t >> 2, lk = (t & 3) * 4;
    const int bk = t >> 4, bn4 = (t & 15) * 4;
    int kp = 0;
    bool first = true;
    while (kp < K) {
        int rem = K - kp;
        int pl;
        if (rem >= 2 * KC_PANEL) pl = KC_PANEL;
        else if (rem > KC_PANEL) pl = (rem / 2 + 15) & ~15;
        else pl = rem;
        const int kend = kp + pl;
        float pacc[4][4] = {};
        for (int k0 = kp; k0 < kend; k0 += 16) {
            __syncthreads();
            float4 av = *(const float4*)&X[(size_t)(bm + lm) * K + k0 + lk];
            aT[lk + 0][lm] = av.x; aT[lk + 1][lm] = av.y;
            aT[lk + 2][lm] = av.z; aT[lk + 3][lm] = av.w;
            *(float4*)&bT[bk][bn4] = *(const float4*)&W[(size_t)(k0 + bk) * E_DIM + bn + bn4];
            __syncthreads();
#pragma unroll
            for (int k = 0; k < 16; ++k) {
                float4 a = *(const float4*)&aT[k][tm * 4];
                float4 b = *(const float4*)&bT[k][tn * 4];
                float qa[4] = {a.x, a.y, a.z, a.w};
                float ea[4] = {b.x, b.y, b.z, b.w};
#pragma unroll
                for (int i = 0; i < 4; ++i)
#pragma unroll
                    for (int j = 0; j < 4; ++j) pacc[i][j] = fmaf(qa[i], ea[j], pacc[i][j]);
            }
        }
        if (first) {
#pragma unroll
            for (int i = 0; i < 4; ++i)
#pragma unroll
                for (int j = 0; j < 4; ++j) cacc[i][j] = pacc[i][j];
        } else {
#pragma unroll
            for (int i = 0; i < 4; ++i)
#pragma unroll
                for (int j = 0; j < 4; ++j) cacc[i][j] = __fadd_rn(cacc[i][j], pacc[i][j]);
        }
        first = false;
        kp = kend;
    }
#pragma unroll
    for (int i = 0; i < 4; ++i) {
        float4 v = make_float4(cacc[i][0], cacc[i][1], cacc[i][2], cacc[i][3]);
        *(float4*)&Y[(size_t)(bm + tm * 4 + i) * E_DIM + bn + tn * 4] = v;
    }
}

__global__ __launch_bounds__(256) void agg_kernel(const float* __restrict__ xw,
                                                  const int* __restrict__ rowstart,
                                                  const int* __restrict__ col,
                                                  const float* __restrict__ dinv,
                                                  const float* __restrict__ bias,
                                                  float* __restrict__ out, int do_relu) {
    int i = blockIdx.x;
    int c = threadIdx.x;
    float di = dinv[i];
    float acc = 0.0f;
    int s0 = rowstart[i], s1 = rowstart[i + 1];
    for (int j = s0; j < s1; ++j) {
        int s = col[j];
        float nrm = __fmul_rn(dinv[s], di);
        acc = __fadd_rn(acc, __fmul_rn(nrm, xw[(size_t)s * E_DIM + c]));
    }
    acc = __fadd_rn(acc, __fmul_rn(__fmul_rn(di, di), xw[(size_t)i * E_DIM + c]));
    acc = __fadd_rn(acc, bias[c]);
    if (do_relu) acc = fmaxf(acc, 0.0f);
    out[(size_t)i * E_DIM + c] = acc;
}

// numpy-pairwise bitexact squared row norms
__global__ __launch_bounds__(256) void enorm_kernel(const float* __restrict__ e,
                                                    float* __restrict__ out) {
    int t = threadIdx.x;
    int row = blockIdx.x * 16 + (t >> 4);
    int l = t & 15;
    int blk = l >> 3, j = l & 7;
    const float* p = e + (size_t)row * 256 + blk * 128 + j;
    float v = p[0];
    float acc = __fmul_rn(v, v);
#pragma unroll
    for (int i = 1; i < 16; ++i) {
        float w = p[i * 8];
        acc = __fadd_rn(acc, __fmul_rn(w, w));
    }
    acc = __fadd_rn(acc, __shfl_xor(acc, 1, 64));
    acc = __fadd_rn(acc, __shfl_xor(acc, 2, 64));
    acc = __fadd_rn(acc, __shfl_xor(acc, 4, 64));
    acc = __fadd_rn(acc, __shfl_xor(acc, 8, 64));
    if (l == 0) out[row] = acc;
}

__global__ __launch_bounds__(256) void qnorm_kernel(const float* __restrict__ z,
                                                    float* __restrict__ out) {
    int t = threadIdx.x;
    int row = blockIdx.x * 16 + (t >> 4);
    int half = row >> 14, r = row & 16383;
    int b = r >> 8, pp = r & 255;
    int l = t & 15;
    int blk = l >> 3, j = l & 7;
    const float* p = z + (size_t)b * 131072 + (size_t)half * 65536 + pp +
                     (size_t)(blk * 128 + j) * 256;
    float v = p[0];
    float acc = __fmul_rn(v, v);
#pragma unroll
    for (int i = 1; i < 16; ++i) {
        float w = p[(size_t)i * 8 * 256];
        acc = __fadd_rn(acc, __fmul_rn(w, w));
    }
    acc = __fadd_rn(acc, __shfl_xor(acc, 1, 64));
    acc = __fadd_rn(acc, __shfl_xor(acc, 2, 64));
    acc = __fadd_rn(acc, __shfl_xor(acc, 4, 64));
    acc = __fadd_rn(acc, __shfl_xor(acc, 8, 64));
    if (l == 0) out[row] = acc;
}

// Fused distance + per-part top-k. Scores bit-identical to reference:
// dot = sequential k-ascending fp32 FMA chain; s = fl(fl(|z|^2+|e|^2) - fl(2*dot)).
// r7-proven register footprint: acc[4][4], separate float score / int idx arrays.
// Block: 32 queries x 2048 codes (EP=2 splits); per-part sorted top-TK packed to
// u64 keys ((bits(s)<<32)|idx, s>0) only at the end. Ties -> LOWER index.
template <int TK>
__device__ __forceinline__ void quant_body(const float* __restrict__ z,
                                           const float* __restrict__ emb,
                                           const float* __restrict__ en2,
                                           const float* __restrict__ qn2,
                                           unsigned long long* __restrict__ topWs,
                                           int coff) {
    __shared__ float eT[32][132];   // [k][e^f(k)] 128-code tile, swizzled
    __shared__ float qS[32][36];    // [k][q] 32-query slice, re-staged per kc
    __shared__ float sEn2[128];

    const int t = threadIdx.x;
    const int qt = blockIdx.x >> 1;
    const int ep = blockIdx.x & 1;
    const int r0 = qt * 32;
    const int b = r0 >> 8;
    const int p0 = r0 & 255;
    const int e00 = ep * 2048;

    const int tq = t >> 5, te = t & 31;
    const int q0 = tq * 4;
    const int e0 = te * 4;

    const int sk = (t & 7) * 4;      // eT staging rows sk..sk+3 (f = sk&24 uniform)
    const int se = t >> 3;           // eT staging code index within 32-group? no: 0..31 code base
    const int cb = se ^ (sk & 24);   // swizzled column
    const int kq = t >> 3, jq = (t & 7) * 4;  // qS staging

    const float* zb = z + (size_t)b * 131072 + (size_t)coff * 256 + p0;

    float aq[4];
#pragma unroll
    for (int i = 0; i < 4; ++i) aq[i] = qn2[r0 + q0 + i];

    float bsr[4][TK];
    int bir[4][TK];
#pragma unroll
    for (int i = 0; i < 4; ++i)
#pragma unroll
        for (int j = 0; j < TK; ++j) { bsr[i][j] = 3.4e38f; bir[i][j] = 0; }

    for (int et = 0; et < 16; ++et) {
        const int ebase = e00 + et * 128;
        float acc[4][4] = {};
        for (int kc = 0; kc < 8; ++kc) {
            __syncthreads();
            // stage eT: 128 codes x 32 dims, transposed + swizzled (4 codes/thread)
#pragma unroll
            for (int i = 0; i < 4; ++i) {
                float4 v = *(const float4*)&emb[(size_t)(ebase + se + 32 * i) * 256 + kc * 32 + sk];
                eT[sk + 0][cb + 32 * i] = v.x;
                eT[sk + 1][cb + 32 * i] = v.y;
                eT[sk + 2][cb + 32 * i] = v.z;
                eT[sk + 3][cb + 32 * i] = v.w;
            }
            // stage qS: 32 q x 32 k slice of z (coalesced float4 over queries)
            *(float4*)&qS[kq][jq] = *(const float4*)&zb[(size_t)(kc * 32 + kq) * 256 + jq];
            if (kc == 0 && t < 128) sEn2[t] = en2[ebase + t];
            __syncthreads();
#pragma unroll
            for (int k = 0; k < 32; ++k) {
                const int f = k & 24;
                float4 ev4 = *(const float4*)&eT[k][e0 ^ f];
                float4 qv4 = *(const float4*)&qS[k][q0];
                float qa[4] = {qv4.x, qv4.y, qv4.z, qv4.w};
                float ea[4] = {ev4.x, ev4.y, ev4.z, ev4.w};
#pragma unroll
                for (int i = 0; i < 4; ++i)
#pragma unroll
                    for (int j = 0; j < 4; ++j) acc[i][j] = fmaf(qa[i], ea[j], acc[i][j]);
            }
        }
        // score with reference-identical rounding; per-thread top-k (gi ascending)
#pragma unroll
        for (int j = 0; j < 4; ++j) {
            float e2 = sEn2[e0 + j];
            int gi = ebase + e0 + j;
#pragma unroll
            for (int i = 0; i < 4; ++i) {
                float t1 = __fadd_rn(aq[i], e2);
                float s = __fsub_rn(t1, __fmul_rn(2.0f, acc[i][j]));
                if (s < bsr[i][TK - 1]) {
                    bsr[i][TK - 1] = s; bir[i][TK - 1] = gi;
#pragma unroll
                    for (int m = TK - 1; m > 0; --m) {
                        if (bsr[i][m] < bsr[i][m - 1]) {
                            float tf = bsr[i][m]; bsr[i][m] = bsr[i][m - 1]; bsr[i][m - 1] = tf;
                            int ti2 = bir[i][m]; bir[i][m] = bir[i][m - 1]; bir[i][m - 1] = ti2;
                        }
                    }
                }
            }
        }
    }

    // butterfly merge across the 32 lanes sharing each query group; ties -> lower idx
#pragma unroll
    for (int mw = 1; mw < 32; mw <<= 1) {
#pragma unroll
        for (int i = 0; i < 4; ++i) {
            float ms[TK], os[TK], ns[TK];
            int mi[TK], oi[TK], ni[TK];
#pragma unroll
            for (int j = 0; j < TK; ++j) {
                ms[j] = bsr[i][j]; mi[j] = bir[i][j];
                os[j] = __shfl_xor(bsr[i][j], mw, 64);
                oi[j] = __shfl_xor(bir[i][j], mw, 64);
            }
#pragma unroll
            for (int x = 0; x < TK; ++x) {
                bool ta = (ms[0] < os[0]) || (ms[0] == os[0] && mi[0] < oi[0]);
                ns[x] = ta ? ms[0] : os[0];
                ni[x] = ta ? mi[0] : oi[0];
#pragma unroll
                for (int y = 0; y < TK - 1; ++y) {
                    ms[y] = ta ? ms[y + 1] : ms[y];
                    mi[y] = ta ? mi[y + 1] : mi[y];
                    os[y] = ta ? os[y] : os[y + 1];
                    oi[y] = ta ? oi[y] : oi[y + 1];
                }
            }
#pragma unroll
            for (int j = 0; j < TK; ++j) { bsr[i][j] = ns[j]; bir[i][j] = ni[j]; }
        }
    }

    if (te == 0) {
#pragma unroll
        for (int i = 0; i < 4; ++i) {
            unsigned long long* dst = topWs + ((size_t)(r0 + q0 + i) * 2 + ep) * TK;
#pragma unroll
            for (int j = 0; j < TK; ++j)
                dst[j] = ((unsigned long long)__float_as_uint(bsr[i][j]) << 32) |
                         (unsigned int)bir[i][j];
        }
    }
}

__global__ __launch_bounds__(256) void quantA_kernel(const float* __restrict__ z,
                                                     const float* __restrict__ emb,
                                                     const float* __restrict__ en2,
                                                     const float* __restrict__ qn2,
                                                     unsigned long long* __restrict__ topWs) {
    quant_body<4>(z, emb, en2, qn2, topWs, 0);
}

__global__ __launch_bounds__(256) void quantN_kernel(const float* __restrict__ z,
                                                     const float* __restrict__ emb,
                                                     const float* __restrict__ en2,
                                                     const float* __restrict__ qn2,
                                                     unsigned long long* __restrict__ topWs) {
    quant_body<1>(z, emb, en2, qn2, topWs, 256);
}

// merge 2 sorted-4 lists -> top4; straight-through output + loss (adjective half)
__global__ __launch_bounds__(256) void mergeA_kernel(const unsigned long long* __restrict__ topWs,
                                                     const float* __restrict__ z,
                                                     const float* __restrict__ emb,
                                                     float* __restrict__ out,
                                                     float* __restrict__ lossAcc) {
    __shared__ int sIdx[32][4];
    __shared__ float red[256];
    const int t = threadIdx.x;
    const int r0 = blockIdx.x * 32;
    const int b = r0 >> 8, p0 = r0 & 255;
    if (t < 32) {
        const unsigned long long* src = topWs + (size_t)(r0 + t) * 8;
        unsigned long long ms[4], os[4], ns[4];
#pragma unroll
        for (int j = 0; j < 4; ++j) { ms[j] = src[j]; os[j] = src[4 + j]; }
#pragma unroll
        for (int x = 0; x < 4; ++x) {
            bool ta = ms[0] < os[0];
            ns[x] = ta ? ms[0] : os[0];
#pragma unroll
            for (int y = 0; y < 3; ++y) {
                ms[y] = ta ? ms[y + 1] : ms[y];
                os[y] = ta ? os[y] : os[y + 1];
            }
        }
        int pp = p0 + t;
#pragma unroll
        for (int j = 0; j < 4; ++j) {
            int idx = (int)(unsigned int)(ns[j] & 0xffffffffull);
            sIdx[t][j] = idx;
            out[IDX_OFF + (size_t)b * 1280 + pp * 4 + j] = (float)idx;
        }
    }
    __syncthreads();
    float lsum = 0.0f;
    {
        const int q = t & 31;
        const int pp = p0 + q;
        float* ob = out + (size_t)b * 131072 + pp;
        const float* zb = z + (size_t)b * 131072 + pp;
        int id[4];
#pragma unroll
        for (int j = 0; j < 4; ++j) id[j] = sIdx[q][j];
        for (int i = 0; i < 32; ++i) {
            int c = (t >> 5) + 8 * i;
            float v = 0.0f;
#pragma unroll
            for (int j = 0; j < 4; ++j) v = __fadd_rn(v, emb[(size_t)id[j] * 256 + c]);
            v *= 0.25f;
            float dd = v - zb[(size_t)c * 256];
            lsum += dd * dd;
            ob[(size_t)c * 256] = v;
        }
    }
    red[t] = lsum;
    __syncthreads();
    for (int s2 = 128; s2 > 0; s2 >>= 1) {
        if (t < s2) red[t] += red[t + s2];
        __syncthreads();
    }
    if (t == 0) atomicAdd(lossAcc, red[0]);
}

// min of 2 parts; straight-through output + loss (noun half)
__global__ __launch_bounds__(256) void mergeN_kernel(const unsigned long long* __restrict__ topWs,
                                                     const float* __restrict__ z,
                                                     const float* __restrict__ emb,
                                                     float* __restrict__ out,
                                                     float* __restrict__ lossAcc) {
    __shared__ int sIdx[32];
    __shared__ float red[256];
    const int t = threadIdx.x;
    const int r0 = blockIdx.x * 32;
    const int b = r0 >> 8, p0 = r0 & 255;
    if (t < 32) {
        const unsigned long long* src = topWs + (size_t)(r0 + t) * 2;
        unsigned long long k0 = src[0], k1 = src[1];
        unsigned long long mm = (k0 < k1) ? k0 : k1;
        int idx = (int)(unsigned int)(mm & 0xffffffffull);
        sIdx[t] = idx;
        out[IDX_OFF + (size_t)b * 1280 + 1024 + p0 + t] = (float)idx;
    }
    __syncthreads();
    float lsum = 0.0f;
    {
        const int q = t & 31;
        const int pp = p0 + q;
        float* ob = out + (size_t)b * 131072 + 65536 + pp;
        const float* zb = z + (size_t)b * 131072 + 65536 + pp;
        int id = sIdx[q];
        for (int i = 0; i < 32; ++i) {
            int c = (t >> 5) + 8 * i;
            float v = emb[(size_t)id * 256 + c];
            float dd = v - zb[(size_t)c * 256];
            lsum += dd * dd;
            ob[(size_t)c * 256] = v;
        }
    }
    red[t] = lsum;
    __syncthreads();
    for (int s2 = 128; s2 > 0; s2 >>= 1) {
        if (t < s2) red[t] += red[t + s2];
        __syncthreads();
    }
    if (t == 0) atomicAdd(lossAcc, red[0]);
}

__global__ void final_kernel(const float* __restrict__ lossAcc, float* __restrict__ out) {
    if (threadIdx.x == 0 && blockIdx.x == 0) {
        const float inv = 1.0f / 4194304.0f;
        float mseA = lossAcc[0] * inv;
        float mseN = lossAcc[1] * inv;
        float quan = mseA + mseN;
        float commit = 0.25f * mseA + 0.25f * mseN;
        out[LOSS_OFF + 0] = quan + commit;
        out[LOSS_OFF + 1] = commit;
        out[LOSS_OFF + 2] = quan;
    }
}

extern "C" void kernel_launch(void* const* d_in, const int* in_sizes, int n_in,
                              void* d_out, int out_size, void* d_ws, size_t ws_size,
                              hipStream_t stream) {
    const float* z = (const float*)d_in[0];
    const float* node_x = (const float*)d_in[1];
    const int* ei = (const int*)d_in[2];
    const float* W1 = (const float*)d_in[3];
    const float* b1 = (const float*)d_in[4];
    const float* W2 = (const float*)d_in[5];
    const float* b2 = (const float*)d_in[6];
    float* out = (float*)d_out;
    float* ws = (float*)d_ws;

    float* dinv = ws + WS_DINV;
    float* en2 = ws + WS_EN2;
    float* lossAcc = ws + WS_LOSS;
    int* cnt = (int*)(ws + WS_CNT);
    int* rowstart = (int*)(ws + WS_ROWSTART);
    int* fill = (int*)(ws + WS_FILL);
    int* col = (int*)(ws + WS_COL);
    float* xw = ws + WS_XW;
    float* h = ws + WS_H;
    float* tew = ws + WS_TEW;
    float* qn2 = ws + WS_QN2;
    unsigned long long* topA = (unsigned long long*)(ws + WS_XW);  // reuse xw after agg2
    unsigned long long* topN = topA + 131072;

    const int* srcp = ei;
    const int* dstp = ei + N_EDGES;

    hipMemsetAsync(cnt, 0, N_NODES * sizeof(int), stream);
    hipMemsetAsync(fill, 0, N_NODES * sizeof(int), stream);
    hipMemsetAsync(lossAcc, 0, 2 * sizeof(float), stream);

    count_kernel<<<N_EDGES / 256, 256, 0, stream>>>(dstp, cnt);
    scan_kernel<<<1, 1024, 0, stream>>>(cnt, rowstart, dinv);
    scatter_kernel<<<N_EDGES / 256, 256, 0, stream>>>(dstp, rowstart, fill, col);
    sort_kernel<<<N_NODES / 256, 256, 0, stream>>>(srcp, rowstart, col);

    qnorm_kernel<<<2048, 256, 0, stream>>>(z, qn2);

    gemm_kernel<<<dim3(128, 4), 256, 0, stream>>>(node_x, W1, xw, 1024);
    agg_kernel<<<N_NODES, 256, 0, stream>>>(xw, rowstart, col, dinv, b1, h, 1);
    gemm_kernel<<<dim3(128, 4), 256, 0, stream>>>(h, W2, xw, 256);
    agg_kernel<<<N_NODES, 256, 0, stream>>>(xw, rowstart, col, dinv, b2, tew, 0);

    enorm_kernel<<<512, 256, 0, stream>>>(tew, en2);

    quantA_kernel<<<1024, 256, 0, stream>>>(z, tew, en2, qn2, topA);
    quantN_kernel<<<1024, 256, 0, stream>>>(z, tew + (size_t)NE_HALF * E_DIM,
                                            en2 + NE_HALF, qn2 + 16384, topN);
    mergeA_kernel<<<512, 256, 0, stream>>>(topA, z, tew, out, lossAcc + 0);
    mergeN_kernel<<<512, 256, 0, stream>>>(topN, z, tew + (size_t)NE_HALF * E_DIM,
                                           out, lossAcc + 1);
    final_kernel<<<1, 64, 0, stream>>>(lossAcc, out);
}